// Round 2
// baseline (982.615 us; speedup 1.0000x reference)
//
#include <hip/hip_runtime.h>

typedef unsigned short u16;
typedef __attribute__((ext_vector_type(8))) short short8;
typedef __attribute__((ext_vector_type(4))) short short4v;
typedef __attribute__((ext_vector_type(4))) float float4v;

__device__ __forceinline__ u16 f2b(float f) {
  union { float f; unsigned u; } v; v.f = f;
  unsigned r = v.u + 0x7fffu + ((v.u >> 16) & 1u);
  return (u16)(r >> 16);
}

#define AS1(p) ((const __attribute__((address_space(1))) void*)(p))
#define AS3(p) ((__attribute__((address_space(3))) void*)(p))

// ---------------- f32 -> bf16, contiguous ----------------
__global__ __launch_bounds__(256) void cvt_bf16_kernel(const float* __restrict__ in,
                                                       u16* __restrict__ out, long n) {
  long i = ((long)blockIdx.x * 256 + threadIdx.x) * 8;
  if (i + 8 > n) return;
  float4v a = *(const float4v*)(in + i);
  float4v b = *(const float4v*)(in + i + 4);
  short8 o;
  o[0] = (short)f2b(a[0]); o[1] = (short)f2b(a[1]);
  o[2] = (short)f2b(a[2]); o[3] = (short)f2b(a[3]);
  o[4] = (short)f2b(b[0]); o[5] = (short)f2b(b[1]);
  o[6] = (short)f2b(b[2]); o[7] = (short)f2b(b[3]);
  *(short8*)(out + i) = o;
}

// ------- transpose+convert: in[rows][cols] f32 -> out[cols][rows] bf16 -------
__global__ __launch_bounds__(256) void transpose_cvt_kernel(const float* __restrict__ in,
                                                            u16* __restrict__ out,
                                                            int rows, int cols) {
  __shared__ float tile[32][33];
  int bx = blockIdx.x * 32;
  int by = blockIdx.y * 32;
  int tx = threadIdx.x & 31, ty = threadIdx.x >> 5;
  for (int r = ty; r < 32; r += 8)
    tile[r][tx] = in[(long)(by + r) * cols + bx + tx];
  __syncthreads();
  for (int r = ty; r < 32; r += 8)
    out[(long)(bx + r) * rows + by + tx] = f2b(tile[tx][r]);
}

// ------- GEMM: C[M,N] = A[M,K] * B[N,K]^T + bias[N]; m97-style 128x128 tile -------
__global__ __launch_bounds__(256, 2) void gemm_bt_bias(const u16* __restrict__ A,
                                                       const u16* __restrict__ B,
                                                       const float* __restrict__ bias,
                                                       void* __restrict__ Cout,
                                                       int M, int N, int K, int out_bf16) {
  __shared__ __align__(16) u16 As[128 * 32];
  __shared__ __align__(16) u16 Bs[128 * 32];
  const int t = threadIdx.x;
  const int lane = t & 63;
  const int w = t >> 6;
  const int wm = w >> 1, wn = w & 1;
  const int lm = lane & 15, lq = lane >> 4;
  const long row0 = (long)blockIdx.y * 128;
  const long col0 = (long)blockIdx.x * 128;
  float4v acc[4][4] = {};

  const int u0 = t, u1 = t + 256;
  const u16* Ag0 = A + (row0 + (u0 >> 2)) * K + (u0 & 3) * 8;
  const u16* Ag1 = A + (row0 + (u1 >> 2)) * K + (u1 & 3) * 8;
  const u16* Bg0 = B + (col0 + (u0 >> 2)) * K + (u0 & 3) * 8;
  const u16* Bg1 = B + (col0 + (u1 >> 2)) * K + (u1 & 3) * 8;
  u16* lA0 = As + u0 * 8;  u16* lA1 = As + u1 * 8;
  u16* lB0 = Bs + u0 * 8;  u16* lB1 = Bs + u1 * 8;

  for (int kb = 0; kb < K; kb += 32) {
    __builtin_amdgcn_global_load_lds(AS1(Ag0 + kb), AS3(lA0), 16, 0, 0);
    __builtin_amdgcn_global_load_lds(AS1(Ag1 + kb), AS3(lA1), 16, 0, 0);
    __builtin_amdgcn_global_load_lds(AS1(Bg0 + kb), AS3(lB0), 16, 0, 0);
    __builtin_amdgcn_global_load_lds(AS1(Bg1 + kb), AS3(lB1), 16, 0, 0);
    __syncthreads();
    short8 af[4], bf[4];
#pragma unroll
    for (int i = 0; i < 4; i++)
      af[i] = *(const short8*)(As + (wm * 64 + i * 16 + lm) * 32 + lq * 8);
#pragma unroll
    for (int i = 0; i < 4; i++)
      bf[i] = *(const short8*)(Bs + (wn * 64 + i * 16 + lm) * 32 + lq * 8);
#pragma unroll
    for (int mt = 0; mt < 4; mt++)
#pragma unroll
      for (int nt = 0; nt < 4; nt++)
        acc[mt][nt] = __builtin_amdgcn_mfma_f32_16x16x32_bf16(af[mt], bf[nt], acc[mt][nt], 0, 0, 0);
    __syncthreads();
  }

#pragma unroll
  for (int nt = 0; nt < 4; nt++) {
    long cg = col0 + wn * 64 + nt * 16 + lm;
    float bv = bias[cg];
#pragma unroll
    for (int mt = 0; mt < 4; mt++) {
      long rbase = row0 + wm * 64 + mt * 16 + lq * 4;
#pragma unroll
      for (int r = 0; r < 4; r++) {
        float v = acc[mt][nt][r] + bv;
        long idx = (rbase + r) * N + cg;
        if (out_bf16) ((u16*)Cout)[idx] = f2b(v);
        else          ((float*)Cout)[idx] = v;
      }
    }
  }
}

// ------- Per-position head-mixing attention (matches the reference einsum!) -------
// For each (b,s): scores[h][t] = q_h . k_t / sqrt(128)  (16x16), softmax over t,
// context[h][d] = sum_t w[h][t] v[t][d]. Output written in (B,H,S,D) flat order,
// which IS the reference's transpose(0,2,1,3).reshape row-major view.
// One wave per position; 4 positions per 256-thread block.
__global__ __launch_bounds__(256) void head_attn_kernel(const u16* __restrict__ qkv,
                                                        u16* __restrict__ ctx) {
  __shared__ __align__(16) u16 vt_s[4][128 * 16];  // per-wave V^T: vt[d][t]
  __shared__ __align__(16) u16 ws_s[4][16 * 32];   // per-wave W: ws[h][t], t padded to 32
  const int tid = threadIdx.x;
  const int lane = tid & 63;
  const int w = tid >> 6;
  const int lm = lane & 15, lq = lane >> 4;
  const int pos = blockIdx.x * 4 + w;             // 0..16383 = b*4096 + s
  const int b = pos >> 12, s = pos & 4095;
  const long rowb = (long)pos * 6144;

  u16* vt = vt_s[w];
  u16* wsp = ws_s[w];

  // zero weight tile (incl. K-pad cols 16..31 -> dead MFMA K-lanes contribute 0)
  for (int i = lane; i < 16 * 32; i += 64) wsp[i] = 0;

  // stage V^T: coalesced global reads (lane covers v[t=lane>>2][32-d slice])
  {
    int tt = lane >> 2, db = (lane & 3) * 32;
#pragma unroll
    for (int c = 0; c < 4; c++) {
      short8 vv = *(const short8*)(qkv + rowb + 4096 + tt * 128 + db + c * 8);
#pragma unroll
      for (int j = 0; j < 8; j++)
        vt[(db + c * 8 + j) * 16 + tt] = (u16)vv[j];
    }
  }
  __syncthreads();

  // scores = q @ k^T : A[m=h][k=d], B[k=d][n=t], K=128 via 4 x mfma 16x16x32
  float4v st = {0.f, 0.f, 0.f, 0.f};
#pragma unroll
  for (int ks = 0; ks < 4; ks++) {
    short8 qa = *(const short8*)(qkv + rowb + lm * 128 + ks * 32 + lq * 8);
    short8 kb = *(const short8*)(qkv + rowb + 2048 + lm * 128 + ks * 32 + lq * 8);
    st = __builtin_amdgcn_mfma_f32_16x16x32_bf16(qa, kb, st, 0, 0, 0);
  }

  // softmax over t (= lane lm) per row h = lq*4+r; write normalized bf16 w to LDS
  const float sc = 0.08838834764831845f * 1.4426950408889634f; // 1/sqrt(128)*log2(e)
#pragma unroll
  for (int r = 0; r < 4; r++) {
    float z = st[r] * sc;
    float m = z;
    m = fmaxf(m, __shfl_xor(m, 1));
    m = fmaxf(m, __shfl_xor(m, 2));
    m = fmaxf(m, __shfl_xor(m, 4));
    m = fmaxf(m, __shfl_xor(m, 8));
    float p = exp2f(z - m);
    float ss = p;
    ss += __shfl_xor(ss, 1);
    ss += __shfl_xor(ss, 2);
    ss += __shfl_xor(ss, 4);
    ss += __shfl_xor(ss, 8);
    wsp[(lq * 4 + r) * 32 + lm] = f2b(p / ss);
  }
  __syncthreads();

  // context = w @ v : A[m=h][k=t (pad32)], B[k=t][n=d], 8 d-tiles of 16
  short8 wa = *(const short8*)(wsp + lm * 32 + lq * 8);
#pragma unroll
  for (int dt = 0; dt < 8; dt++) {
    // B frag: v[t=lq*8+j][d=dt*16+lm]; dead K-lanes (lq>=2) re-read valid rows (w=0 there)
    short8 vb = *(const short8*)(vt + (dt * 16 + lm) * 16 + (lq & 1) * 8);
    float4v o = {0.f, 0.f, 0.f, 0.f};
    o = __builtin_amdgcn_mfma_f32_16x16x32_bf16(wa, vb, o, 0, 0, 0);
    // D: row = h = lq*4+r, col = d = dt*16+lm; write to (B,H,S,D) flat
#pragma unroll
    for (int r = 0; r < 4; r++) {
      int h = lq * 4 + r;
      ctx[(((long)(b * 16 + h) * 4096 + s) * 128) + dt * 16 + lm] = f2b(o[r]);
    }
  }
}

extern "C" void kernel_launch(void* const* d_in, const int* in_sizes, int n_in,
                              void* d_out, int out_size, void* d_ws, size_t ws_size,
                              hipStream_t stream) {
  const float* x     = (const float*)d_in[0];  // [4,4096,2048]
  const float* Wqkv  = (const float*)d_in[1];  // [2048,6144]
  const float* bqkv  = (const float*)d_in[2];  // [6144]
  const float* Wproj = (const float*)d_in[3];  // [2048,2048]
  const float* bproj = (const float*)d_in[4];  // [2048]
  float* out = (float*)d_out;                  // [4,4096,2048] f32

  // workspace layout (bf16 elements)
  u16* xb     = (u16*)d_ws;                    // 33,554,432
  u16* WqkvT  = xb + 33554432L;                // 12,582,912  (6144 x 2048)
  u16* WprojT = WqkvT + 12582912L;             //  4,194,304  (2048 x 2048)
  u16* qkvb   = WprojT + 4194304L;             // 100,663,296 (16384 x 6144)
  u16* ctxb   = qkvb + 100663296L;             // 33,554,432  (B,H,S,D) flat

  cvt_bf16_kernel<<<33554432L / 2048, 256, 0, stream>>>(x, xb, 33554432L);
  transpose_cvt_kernel<<<dim3(6144 / 32, 2048 / 32), 256, 0, stream>>>(Wqkv, WqkvT, 2048, 6144);
  transpose_cvt_kernel<<<dim3(2048 / 32, 2048 / 32), 256, 0, stream>>>(Wproj, WprojT, 2048, 2048);

  // qkv = x @ Wqkv + bqkv  (bf16 out)
  gemm_bt_bias<<<dim3(6144 / 128, 16384 / 128), 256, 0, stream>>>(
      xb, WqkvT, bqkv, qkvb, 16384, 6144, 2048, 1);

  // per-position head-mixing attention -> context in (B,H,S,D) order (bf16)
  head_attn_kernel<<<4096, 256, 0, stream>>>(qkvb, ctxb);

  // out = ctx_view @ Wproj + bproj (f32 out)
  gemm_bt_bias<<<dim3(2048 / 128, 16384 / 128), 256, 0, stream>>>(
      ctxb, WprojT, bproj, out, 16384, 2048, 2048, 0);
}